// Round 2
// baseline (2505.750 us; speedup 1.0000x reference)
//
#include <hip/hip_runtime.h>
#include <hip/hip_fp16.h>

#define N_NODES 100000
#define N_EDGES 1600000
#define NBLK    391          // ceil(N_NODES/256)

__device__ __forceinline__ float bcf(float v, int l) {
    return __int_as_float(__builtin_amdgcn_readlane(__float_as_int(v), l));
}
__device__ __forceinline__ int bci(int v, int l) {
    return __builtin_amdgcn_readlane(v, l);
}

// ---------------- CSR build ----------------

__global__ void k_count(const int* __restrict__ dst, int* __restrict__ cnt) {
    int e = blockIdx.x * 256 + threadIdx.x;
    if (e < N_EDGES) atomicAdd(&cnt[dst[e]], 1);
}

__global__ void k_scan1(const int* __restrict__ cnt, int* __restrict__ rp,
                        int* __restrict__ bsum, float* __restrict__ dinv) {
    __shared__ int sh[256];
    int t = threadIdx.x;
    int i = blockIdx.x * 256 + t;
    int v = (i < N_NODES) ? cnt[i] : 0;
    if (i < N_NODES) dinv[i] = rsqrtf((float)(v + 1));   // +1 self-loop
    sh[t] = v;
    __syncthreads();
    for (int o = 1; o < 256; o <<= 1) {
        int u = (t >= o) ? sh[t - o] : 0;
        __syncthreads();
        sh[t] += u;
        __syncthreads();
    }
    if (i < N_NODES) rp[i] = sh[t] - v;
    if (t == 255) bsum[blockIdx.x] = sh[t];
}

__global__ void k_scan2(const int* __restrict__ bsum, int* __restrict__ bo, int nb) {
    __shared__ int sh[512];
    int t = threadIdx.x;
    sh[t] = (t < nb) ? bsum[t] : 0;
    __syncthreads();
    for (int o = 1; o < 512; o <<= 1) {
        int u = (t >= o) ? sh[t - o] : 0;
        __syncthreads();
        sh[t] += u;
        __syncthreads();
    }
    if (t <= nb) bo[t] = (t == 0) ? 0 : sh[t - 1];
}

__global__ void k_scan3(int* __restrict__ rp, const int* __restrict__ bo, int nb) {
    int i = blockIdx.x * 256 + threadIdx.x;
    if (i < N_NODES)       rp[i] += bo[i >> 8];
    else if (i == N_NODES) rp[N_NODES] = bo[nb];
}

__global__ void k_fill(const int* __restrict__ src, const int* __restrict__ dst,
                       const int* __restrict__ rp, int* __restrict__ fill,
                       int* __restrict__ col) {
    int e = blockIdx.x * 256 + threadIdx.x;
    if (e < N_EDGES) {
        int d = dst[e];
        int pos = atomicAdd(&fill[d], 1);
        col[rp[d] + pos] = src[e];
    }
}

// ---------------- GEMM1: h1 = x @ W1, fp16 output ----------------

__global__ __launch_bounds__(1024) void k_gemm1(const float* __restrict__ X,
                                                const float* __restrict__ W,
                                                __half* __restrict__ H) {
    __shared__ float sw[128 * 128];
    for (int i = threadIdx.x; i < 128 * 128 / 4; i += 1024)
        reinterpret_cast<float4*>(sw)[i] = reinterpret_cast<const float4*>(W)[i];
    __syncthreads();

    int wv = threadIdx.x >> 6, lane = threadIdx.x & 63;
    int row0 = blockIdx.x * 64 + wv * 4;

    float xr[4][2];
#pragma unroll
    for (int r = 0; r < 4; r++) {
        int row = min(row0 + r, N_NODES - 1);
        const float* xp = X + (size_t)row * 128;
        xr[r][0] = xp[lane];
        xr[r][1] = xp[64 + lane];
    }

    float acc[4][2] = {{0.f, 0.f}, {0.f, 0.f}, {0.f, 0.f}, {0.f, 0.f}};
#pragma unroll
    for (int k = 0; k < 128; k++) {
        float w0 = sw[k * 128 + lane];
        float w1 = sw[k * 128 + 64 + lane];
#pragma unroll
        for (int r = 0; r < 4; r++) {
            float xv = bcf(xr[r][k >> 6], k & 63);
            acc[r][0] += xv * w0;
            acc[r][1] += xv * w1;
        }
    }
#pragma unroll
    for (int r = 0; r < 4; r++) {
        if (row0 + r < N_NODES) {
            __half* hp = H + (size_t)(row0 + r) * 128;
            hp[lane]      = __float2half(acc[r][0]);
            hp[64 + lane] = __float2half(acc[r][1]);
        }
    }
}

// ---------------- fused: h3 = relu(agg(h1) + b1) @ W2, fp16 out ----------------
// one wave per node; 16 nodes per 1024-thread block

__global__ __launch_bounds__(1024) void k_agg1_gemm2(const __half* __restrict__ H1,
                                                     const float* __restrict__ dinv,
                                                     const int* __restrict__ rp,
                                                     const int* __restrict__ col,
                                                     const float* __restrict__ b1,
                                                     const float* __restrict__ W2,
                                                     __half* __restrict__ H3) {
    __shared__ float sw[128 * 64];
    for (int i = threadIdx.x; i < 128 * 64 / 4; i += 1024)
        reinterpret_cast<float4*>(sw)[i] = reinterpret_cast<const float4*>(W2)[i];
    __syncthreads();

    int node = blockIdx.x * 16 + (threadIdx.x >> 6);
    int lane = threadIdx.x & 63;
    const __half2* H1v = reinterpret_cast<const __half2*>(H1);

    float di = dinv[node];
    int e0 = rp[node], e1 = rp[node + 1];

    // self-loop term
    float2 sv = __half22float2(H1v[(size_t)node * 64 + lane]);
    float a0 = sv.x * di * di, a1 = sv.y * di * di;

    for (int cb = e0; cb < e1; cb += 64) {
        int n = min(64, e1 - cb);
        int idx = cb + lane;
        int cv = col[idx < e1 ? idx : e0];
        float dv = dinv[cv];

        int j = 0;
        for (; j + 8 <= n; j += 8) {
            float2 v[8];
            float  w[8];
#pragma unroll
            for (int q = 0; q < 8; q++) {
                int s = bci(cv, j + q);
                w[q] = bcf(dv, j + q) * di;
                v[q] = __half22float2(H1v[(size_t)s * 64 + lane]);
            }
#pragma unroll
            for (int q = 0; q < 8; q++) { a0 += v[q].x * w[q]; a1 += v[q].y * w[q]; }
        }
        for (; j < n; j++) {
            int s = bci(cv, j);
            float w = bcf(dv, j) * di;
            float2 v = __half22float2(H1v[(size_t)s * 64 + lane]);
            a0 += v.x * w;
            a1 += v.y * w;
        }
    }

    a0 += b1[2 * lane];
    a1 += b1[2 * lane + 1];
    a0 = fmaxf(a0, 0.f);
    a1 = fmaxf(a1, 0.f);

    // row @ W2 : lane owns output column c = lane
    float acc = 0.f;
#pragma unroll
    for (int l = 0; l < 64; l++) {
        acc += bcf(a0, l) * sw[(2 * l) * 64 + lane];
        acc += bcf(a1, l) * sw[(2 * l + 1) * 64 + lane];
    }
    H3[(size_t)node * 64 + lane] = __float2half(acc);
}

// ---------------- agg2: out = agg(h3) + b2, fp32 out ----------------

__global__ __launch_bounds__(256) void k_agg2(const __half* __restrict__ H3,
                                              const float* __restrict__ dinv,
                                              const int* __restrict__ rp,
                                              const int* __restrict__ col,
                                              const float* __restrict__ b2,
                                              float* __restrict__ out) {
    int node = (blockIdx.x * 256 + threadIdx.x) >> 6;
    int lane = threadIdx.x & 63;
    if (node >= N_NODES) return;

    float di = dinv[node];
    int e0 = rp[node], e1 = rp[node + 1];

    float a = __half2float(H3[(size_t)node * 64 + lane]) * di * di;

    for (int cb = e0; cb < e1; cb += 64) {
        int n = min(64, e1 - cb);
        int idx = cb + lane;
        int cv = col[idx < e1 ? idx : e0];
        float dv = dinv[cv];

        int j = 0;
        for (; j + 8 <= n; j += 8) {
            float hv[8];
            float w[8];
#pragma unroll
            for (int q = 0; q < 8; q++) {
                int s = bci(cv, j + q);
                w[q] = bcf(dv, j + q) * di;
                hv[q] = __half2float(H3[(size_t)s * 64 + lane]);
            }
#pragma unroll
            for (int q = 0; q < 8; q++) a += hv[q] * w[q];
        }
        for (; j < n; j++) {
            int s = bci(cv, j);
            float w = bcf(dv, j) * di;
            a += __half2float(H3[(size_t)s * 64 + lane]) * w;
        }
    }

    out[(size_t)node * 64 + lane] = a + b2[lane];
}

// ---------------- launch ----------------

extern "C" void kernel_launch(void* const* d_in, const int* in_sizes, int n_in,
                              void* d_out, int out_size, void* d_ws, size_t ws_size,
                              hipStream_t stream) {
    const float* x  = (const float*)d_in[0];
    const int*   ei = (const int*)d_in[1];
    const float* W1 = (const float*)d_in[2];
    const float* b1 = (const float*)d_in[3];
    const float* W2 = (const float*)d_in[4];
    const float* b2 = (const float*)d_in[5];
    float* out = (float*)d_out;

    const int* src = ei;
    const int* dst = ei + N_EDGES;

    char* ws = (char*)d_ws;
    size_t off = 0;
    auto alloc = [&](size_t bytes) -> void* {
        off = (off + 255) & ~(size_t)255;
        void* p = ws + off;
        off += bytes;
        return p;
    };
    int*    cnt  = (int*)alloc((size_t)N_NODES * 4);
    int*    fill = (int*)alloc((size_t)N_NODES * 4);
    int*    rp   = (int*)alloc((size_t)(N_NODES + 1) * 4);
    int*    bsum = (int*)alloc((size_t)NBLK * 4);
    int*    bo   = (int*)alloc((size_t)(NBLK + 1) * 4);
    float*  dinv = (float*)alloc((size_t)N_NODES * 4);
    int*    col  = (int*)alloc((size_t)N_EDGES * 4);
    __half* h1   = (__half*)alloc((size_t)N_NODES * 128 * 2);
    __half* h3   = (__half*)alloc((size_t)N_NODES * 64 * 2);

    hipMemsetAsync(cnt, 0, (size_t)N_NODES * 4, stream);
    hipMemsetAsync(fill, 0, (size_t)N_NODES * 4, stream);

    int ebl = (N_EDGES + 255) / 256;

    // CSR build (shared by both layers)
    k_count<<<ebl, 256, 0, stream>>>(dst, cnt);
    k_scan1<<<NBLK, 256, 0, stream>>>(cnt, rp, bsum, dinv);
    k_scan2<<<1, 512, 0, stream>>>(bsum, bo, NBLK);
    k_scan3<<<(N_NODES + 1 + 255) / 256, 256, 0, stream>>>(rp, bo, NBLK);
    k_fill<<<ebl, 256, 0, stream>>>(src, dst, rp, fill, col);

    // layer 1 GEMM: h1 = x @ W1 (fp16 out)
    k_gemm1<<<(N_NODES + 63) / 64, 1024, 0, stream>>>(x, W1, h1);

    // fused: h3 = relu(agg(h1) + b1) @ W2
    k_agg1_gemm2<<<N_NODES / 16, 1024, 0, stream>>>(h1, dinv, rp, col, b1, W2, h3);

    // layer 2 agg: out = agg(h3) + b2
    k_agg2<<<(N_NODES * 64 + 255) / 256, 256, 0, stream>>>(h3, dinv, rp, col, b2, out);
}

// Round 3
// 455.624 us; speedup vs baseline: 5.4996x; 5.4996x over previous
//
#include <hip/hip_runtime.h>
#include <hip/hip_fp16.h>

#define N_NODES 100000
#define N_EDGES 1600000
#define NBLK    391          // ceil(N_NODES/256)

__device__ __forceinline__ float bcf(float v, int l) {
    return __int_as_float(__builtin_amdgcn_readlane(__float_as_int(v), l));
}
__device__ __forceinline__ int bci(int v, int l) {
    return __builtin_amdgcn_readlane(v, l);
}

// ---------------- CSR build ----------------

__global__ void k_count(const int* __restrict__ dst, int* __restrict__ cnt) {
    int e = blockIdx.x * 256 + threadIdx.x;
    if (e < N_EDGES) atomicAdd(&cnt[dst[e]], 1);
}

__global__ void k_scan1(const int* __restrict__ cnt, int* __restrict__ rp,
                        int* __restrict__ bsum, float* __restrict__ dinv) {
    __shared__ int sh[256];
    int t = threadIdx.x;
    int i = blockIdx.x * 256 + t;
    int v = (i < N_NODES) ? cnt[i] : 0;
    if (i < N_NODES) dinv[i] = rsqrtf((float)(v + 1));   // +1 self-loop
    sh[t] = v;
    __syncthreads();
    for (int o = 1; o < 256; o <<= 1) {
        int u = (t >= o) ? sh[t - o] : 0;
        __syncthreads();
        sh[t] += u;
        __syncthreads();
    }
    if (i < N_NODES) rp[i] = sh[t] - v;
    if (t == 255) bsum[blockIdx.x] = sh[t];
}

__global__ void k_scan2(const int* __restrict__ bsum, int* __restrict__ bo, int nb) {
    __shared__ int sh[512];
    int t = threadIdx.x;
    sh[t] = (t < nb) ? bsum[t] : 0;
    __syncthreads();
    for (int o = 1; o < 512; o <<= 1) {
        int u = (t >= o) ? sh[t - o] : 0;
        __syncthreads();
        sh[t] += u;
        __syncthreads();
    }
    if (t <= nb) bo[t] = (t == 0) ? 0 : sh[t - 1];
}

__global__ void k_scan3(int* __restrict__ rp, const int* __restrict__ bo, int nb) {
    int i = blockIdx.x * 256 + threadIdx.x;
    if (i < N_NODES)       rp[i] += bo[i >> 8];
    else if (i == N_NODES) rp[N_NODES] = bo[nb];
}

__global__ void k_fill(const int* __restrict__ src, const int* __restrict__ dst,
                       const int* __restrict__ rp, int* __restrict__ fill,
                       int* __restrict__ col) {
    int e = blockIdx.x * 256 + threadIdx.x;
    if (e < N_EDGES) {
        int d = dst[e];
        int pos = atomicAdd(&fill[d], 1);
        col[rp[d] + pos] = src[e];
    }
}

// ---------------- GEMM1: h1 = x @ W1, __half2 output ----------------
// 256 threads/block (R2 lesson: 1024-thr + 64KB LDS forced 64-VGPR budget ->
// scratch spills -> 6.4GB HBM traffic. Keep VGPR budget loose.)
// Lane owns output column pair (2*lane, 2*lane+1): LDS read is ds_read_b64,
// store is one __half2 (4B/lane), and agg1 reads the same __half2 layout.

__global__ __launch_bounds__(256) void k_gemm1(const float* __restrict__ X,
                                               const float* __restrict__ W,
                                               __half2* __restrict__ H) {
    __shared__ float sw[128 * 128];
    for (int i = threadIdx.x; i < 128 * 128 / 4; i += 256)
        reinterpret_cast<float4*>(sw)[i] = reinterpret_cast<const float4*>(W)[i];
    __syncthreads();
    const float2* swv = reinterpret_cast<const float2*>(sw);

    int wv = threadIdx.x >> 6, lane = threadIdx.x & 63;
    int row0 = blockIdx.x * 16 + wv * 4;   // N_NODES = 16*6250, always in range

    float xr[4][2];
#pragma unroll
    for (int r = 0; r < 4; r++) {
        const float* xp = X + (size_t)(row0 + r) * 128;
        xr[r][0] = xp[lane];
        xr[r][1] = xp[64 + lane];
    }

    float acc[4][2] = {{0.f, 0.f}, {0.f, 0.f}, {0.f, 0.f}, {0.f, 0.f}};
#pragma unroll
    for (int k = 0; k < 128; k++) {
        float2 w = swv[k * 64 + lane];          // cols (2*lane, 2*lane+1)
#pragma unroll
        for (int r = 0; r < 4; r++) {
            float xv = bcf(xr[r][k >> 6], k & 63);
            acc[r][0] += xv * w.x;
            acc[r][1] += xv * w.y;
        }
    }
#pragma unroll
    for (int r = 0; r < 4; r++)
        H[(size_t)(row0 + r) * 64 + lane] = __floats2half2_rn(acc[r][0], acc[r][1]);
}

// ---------------- fused: h3 = relu(agg(h1) + b1) @ W2, fp16 out ----------------
// one wave per node; 4 nodes per 256-thread block (VGPR headroom for the
// 8-deep gather pipeline)

__global__ __launch_bounds__(256) void k_agg1_gemm2(const __half2* __restrict__ H1,
                                                    const float* __restrict__ dinv,
                                                    const int* __restrict__ rp,
                                                    const int* __restrict__ col,
                                                    const float* __restrict__ b1,
                                                    const float* __restrict__ W2,
                                                    __half* __restrict__ H3) {
    __shared__ float sw[128 * 64];
    for (int i = threadIdx.x; i < 128 * 64 / 4; i += 256)
        reinterpret_cast<float4*>(sw)[i] = reinterpret_cast<const float4*>(W2)[i];
    __syncthreads();

    int node = blockIdx.x * 4 + (threadIdx.x >> 6);
    int lane = threadIdx.x & 63;

    float di = dinv[node];
    int e0 = rp[node], e1 = rp[node + 1];

    // self-loop term; lane owns feature pair (2*lane, 2*lane+1)
    float2 sv = __half22float2(H1[(size_t)node * 64 + lane]);
    float a0 = sv.x * di * di, a1 = sv.y * di * di;

    for (int cb = e0; cb < e1; cb += 64) {
        int n = min(64, e1 - cb);
        int idx = cb + lane;
        int cv = col[idx < e1 ? idx : e0];
        float dv = dinv[cv];

        int j = 0;
        for (; j + 8 <= n; j += 8) {
            float2 v[8];
            float  w[8];
#pragma unroll
            for (int q = 0; q < 8; q++) {
                int s = bci(cv, j + q);
                w[q] = bcf(dv, j + q) * di;
                v[q] = __half22float2(H1[(size_t)s * 64 + lane]);
            }
#pragma unroll
            for (int q = 0; q < 8; q++) { a0 += v[q].x * w[q]; a1 += v[q].y * w[q]; }
        }
        for (; j < n; j++) {
            int s = bci(cv, j);
            float w = bcf(dv, j) * di;
            float2 v = __half22float2(H1[(size_t)s * 64 + lane]);
            a0 += v.x * w;
            a1 += v.y * w;
        }
    }

    a0 += b1[2 * lane];
    a1 += b1[2 * lane + 1];
    a0 = fmaxf(a0, 0.f);
    a1 = fmaxf(a1, 0.f);

    // row @ W2 : lane owns output column c = lane; readlane(a0,l) = feature 2l
    float acc = 0.f;
#pragma unroll
    for (int l = 0; l < 64; l++) {
        acc += bcf(a0, l) * sw[(2 * l) * 64 + lane];
        acc += bcf(a1, l) * sw[(2 * l + 1) * 64 + lane];
    }
    H3[(size_t)node * 64 + lane] = __float2half(acc);
}

// ---------------- agg2: out = agg(h3) + b2, fp32 out ----------------

__global__ __launch_bounds__(256) void k_agg2(const __half* __restrict__ H3,
                                              const float* __restrict__ dinv,
                                              const int* __restrict__ rp,
                                              const int* __restrict__ col,
                                              const float* __restrict__ b2,
                                              float* __restrict__ out) {
    int node = (blockIdx.x * 256 + threadIdx.x) >> 6;
    int lane = threadIdx.x & 63;
    if (node >= N_NODES) return;

    float di = dinv[node];
    int e0 = rp[node], e1 = rp[node + 1];

    float a = __half2float(H3[(size_t)node * 64 + lane]) * di * di;

    for (int cb = e0; cb < e1; cb += 64) {
        int n = min(64, e1 - cb);
        int idx = cb + lane;
        int cv = col[idx < e1 ? idx : e0];
        float dv = dinv[cv];

        int j = 0;
        for (; j + 8 <= n; j += 8) {
            float hv[8];
            float w[8];
#pragma unroll
            for (int q = 0; q < 8; q++) {
                int s = bci(cv, j + q);
                w[q] = bcf(dv, j + q) * di;
                hv[q] = __half2float(H3[(size_t)s * 64 + lane]);
            }
#pragma unroll
            for (int q = 0; q < 8; q++) a += hv[q] * w[q];
        }
        for (; j < n; j++) {
            int s = bci(cv, j);
            float w = bcf(dv, j) * di;
            a += __half2float(H3[(size_t)s * 64 + lane]) * w;
        }
    }

    out[(size_t)node * 64 + lane] = a + b2[lane];
}

// ---------------- launch ----------------

extern "C" void kernel_launch(void* const* d_in, const int* in_sizes, int n_in,
                              void* d_out, int out_size, void* d_ws, size_t ws_size,
                              hipStream_t stream) {
    const float* x  = (const float*)d_in[0];
    const int*   ei = (const int*)d_in[1];
    const float* W1 = (const float*)d_in[2];
    const float* b1 = (const float*)d_in[3];
    const float* W2 = (const float*)d_in[4];
    const float* b2 = (const float*)d_in[5];
    float* out = (float*)d_out;

    const int* src = ei;
    const int* dst = ei + N_EDGES;

    char* ws = (char*)d_ws;
    size_t off = 0;
    auto alloc = [&](size_t bytes) -> void* {
        off = (off + 255) & ~(size_t)255;
        void* p = ws + off;
        off += bytes;
        return p;
    };
    int*     cnt  = (int*)alloc((size_t)N_NODES * 4);
    int*     fill = (int*)alloc((size_t)N_NODES * 4);
    int*     rp   = (int*)alloc((size_t)(N_NODES + 1) * 4);
    int*     bsum = (int*)alloc((size_t)NBLK * 4);
    int*     bo   = (int*)alloc((size_t)(NBLK + 1) * 4);
    float*   dinv = (float*)alloc((size_t)N_NODES * 4);
    int*     col  = (int*)alloc((size_t)N_EDGES * 4);
    __half2* h1   = (__half2*)alloc((size_t)N_NODES * 128 * 2);
    __half*  h3   = (__half*)alloc((size_t)N_NODES * 64 * 2);

    hipMemsetAsync(cnt, 0, (size_t)N_NODES * 4, stream);
    hipMemsetAsync(fill, 0, (size_t)N_NODES * 4, stream);

    int ebl = (N_EDGES + 255) / 256;

    // CSR build (shared by both layers)
    k_count<<<ebl, 256, 0, stream>>>(dst, cnt);
    k_scan1<<<NBLK, 256, 0, stream>>>(cnt, rp, bsum, dinv);
    k_scan2<<<1, 512, 0, stream>>>(bsum, bo, NBLK);
    k_scan3<<<(N_NODES + 1 + 255) / 256, 256, 0, stream>>>(rp, bo, NBLK);
    k_fill<<<ebl, 256, 0, stream>>>(src, dst, rp, fill, col);

    // layer 1 GEMM: h1 = x @ W1 (fp16 out)
    k_gemm1<<<N_NODES / 16, 256, 0, stream>>>(x, W1, h1);

    // fused: h3 = relu(agg(h1) + b1) @ W2
    k_agg1_gemm2<<<N_NODES / 4, 256, 0, stream>>>(h1, dinv, rp, col, b1, W2, h3);

    // layer 2 agg: out = agg(h3) + b2
    k_agg2<<<(N_NODES * 64 + 255) / 256, 256, 0, stream>>>(h3, dinv, rp, col, b2, out);
}

// Round 4
// 427.238 us; speedup vs baseline: 5.8650x; 1.0664x over previous
//
#include <hip/hip_runtime.h>
#include <hip/hip_fp16.h>

#define N_NODES 100000
#define N_EDGES 1600000
#define NBLK    391          // ceil(N_NODES/256)

__device__ __forceinline__ float bcf(float v, int l) {
    return __int_as_float(__builtin_amdgcn_readlane(__float_as_int(v), l));
}
__device__ __forceinline__ int bci(int v, int l) {
    return __builtin_amdgcn_readlane(v, l);
}

// ---------------- CSR build ----------------

__global__ void k_count(const int* __restrict__ dst, int* __restrict__ cnt) {
    int e = blockIdx.x * 256 + threadIdx.x;
    if (e < N_EDGES) atomicAdd(&cnt[dst[e]], 1);
}

__global__ void k_scan1(const int* __restrict__ cnt, int* __restrict__ rp,
                        int* __restrict__ bsum, float* __restrict__ dinv) {
    __shared__ int sh[256];
    int t = threadIdx.x;
    int i = blockIdx.x * 256 + t;
    int v = (i < N_NODES) ? cnt[i] : 0;
    if (i < N_NODES) dinv[i] = rsqrtf((float)(v + 1));   // +1 self-loop
    sh[t] = v;
    __syncthreads();
    for (int o = 1; o < 256; o <<= 1) {
        int u = (t >= o) ? sh[t - o] : 0;
        __syncthreads();
        sh[t] += u;
        __syncthreads();
    }
    if (i < N_NODES) rp[i] = sh[t] - v;
    if (t == 255) bsum[blockIdx.x] = sh[t];
}

__global__ void k_scan2(const int* __restrict__ bsum, int* __restrict__ bo, int nb) {
    __shared__ int sh[512];
    int t = threadIdx.x;
    sh[t] = (t < nb) ? bsum[t] : 0;
    __syncthreads();
    for (int o = 1; o < 512; o <<= 1) {
        int u = (t >= o) ? sh[t - o] : 0;
        __syncthreads();
        sh[t] += u;
        __syncthreads();
    }
    if (t <= nb) bo[t] = (t == 0) ? 0 : sh[t - 1];
}

__global__ void k_scan3(int* __restrict__ rp, const int* __restrict__ bo, int nb) {
    int i = blockIdx.x * 256 + threadIdx.x;
    if (i < N_NODES)       rp[i] += bo[i >> 8];
    else if (i == N_NODES) rp[N_NODES] = bo[nb];
}

__global__ void k_fill(const int* __restrict__ src, const int* __restrict__ dst,
                       const int* __restrict__ rp, int* __restrict__ fill,
                       int* __restrict__ col) {
    int e = blockIdx.x * 256 + threadIdx.x;
    if (e < N_EDGES) {
        int d = dst[e];
        int pos = atomicAdd(&fill[d], 1);
        col[rp[d] + pos] = src[e];
    }
}

// ---------------- GEMM1: h1 = x @ W1, __half2 output ----------------
// 256 threads/block (R2 lesson: big blocks + big LDS squeeze VGPR budget ->
// scratch spills). Lane owns column pair (2*lane, 2*lane+1).

__global__ __launch_bounds__(256) void k_gemm1(const float* __restrict__ X,
                                               const float* __restrict__ W,
                                               __half2* __restrict__ H) {
    __shared__ float sw[128 * 128];
    for (int i = threadIdx.x; i < 128 * 128 / 4; i += 256)
        reinterpret_cast<float4*>(sw)[i] = reinterpret_cast<const float4*>(W)[i];
    __syncthreads();
    const float2* swv = reinterpret_cast<const float2*>(sw);

    int wv = threadIdx.x >> 6, lane = threadIdx.x & 63;
    int row0 = blockIdx.x * 16 + wv * 4;   // N_NODES = 16*6250, always in range

    float xr[4][2];
#pragma unroll
    for (int r = 0; r < 4; r++) {
        const float* xp = X + (size_t)(row0 + r) * 128;
        xr[r][0] = xp[lane];
        xr[r][1] = xp[64 + lane];
    }

    float acc[4][2] = {{0.f, 0.f}, {0.f, 0.f}, {0.f, 0.f}, {0.f, 0.f}};
#pragma unroll
    for (int k = 0; k < 128; k++) {
        float2 w = swv[k * 64 + lane];          // cols (2*lane, 2*lane+1)
#pragma unroll
        for (int r = 0; r < 4; r++) {
            float xv = bcf(xr[r][k >> 6], k & 63);
            acc[r][0] += xv * w.x;
            acc[r][1] += xv * w.y;
        }
    }
#pragma unroll
    for (int r = 0; r < 4; r++)
        H[(size_t)(row0 + r) * 64 + lane] = __floats2half2_rn(acc[r][0], acc[r][1]);
}

// ---------------- agg1: h2 = relu(agg(h1) + b1), fp16 out ----------------
// Pure gather, NO LDS -> full occupancy for memory-level parallelism.
// One wave per node; lane owns feature pair (2*lane, 2*lane+1).

__global__ __launch_bounds__(256) void k_agg1(const __half2* __restrict__ H1,
                                              const float* __restrict__ dinv,
                                              const int* __restrict__ rp,
                                              const int* __restrict__ col,
                                              const float* __restrict__ b1,
                                              __half2* __restrict__ H2) {
    int node = blockIdx.x * 4 + (threadIdx.x >> 6);
    int lane = threadIdx.x & 63;

    float di = dinv[node];
    int e0 = rp[node], e1 = rp[node + 1];

    // self-loop term
    float2 sv = __half22float2(H1[(size_t)node * 64 + lane]);
    float a0 = sv.x * di * di, a1 = sv.y * di * di;

    for (int cb = e0; cb < e1; cb += 64) {
        int n = min(64, e1 - cb);
        int idx = cb + lane;
        int cv = col[idx < e1 ? idx : e0];
        float dv = dinv[cv];

        int j = 0;
        for (; j + 8 <= n; j += 8) {
            float2 v[8];
            float  w[8];
#pragma unroll
            for (int q = 0; q < 8; q++) {
                int s = bci(cv, j + q);
                w[q] = bcf(dv, j + q) * di;
                v[q] = __half22float2(H1[(size_t)s * 64 + lane]);
            }
#pragma unroll
            for (int q = 0; q < 8; q++) { a0 += v[q].x * w[q]; a1 += v[q].y * w[q]; }
        }
        for (; j < n; j++) {
            int s = bci(cv, j);
            float w = bcf(dv, j) * di;
            float2 v = __half22float2(H1[(size_t)s * 64 + lane]);
            a0 += v.x * w;
            a1 += v.y * w;
        }
    }

    a0 = fmaxf(a0 + b1[2 * lane], 0.f);
    a1 = fmaxf(a1 + b1[2 * lane + 1], 0.f);
    H2[(size_t)node * 64 + lane] = __floats2half2_rn(a0, a1);
}

// ---------------- gemm2: h3 = h2 @ W2, fp16 out ----------------
// 4 nodes per wave: each weight read from LDS is applied to 4 rows
// (amortizes LDS traffic 32KB/node -> 4KB/node). W2 as half2 pairs:
// swp[f*64+c] = (W2[2f][c], W2[2f+1][c]) so one ds_read_b32 feeds 2 fma.

__global__ __launch_bounds__(256) void k_gemm2(const __half2* __restrict__ H2,
                                               const float* __restrict__ W2,
                                               __half* __restrict__ H3) {
    __shared__ __half2 swp[64 * 64];
    for (int idx = threadIdx.x; idx < 64 * 64; idx += 256) {
        int f = idx >> 6, c = idx & 63;
        swp[idx] = __floats2half2_rn(W2[(2 * f) * 64 + c], W2[(2 * f + 1) * 64 + c]);
    }
    __syncthreads();

    int wv = threadIdx.x >> 6, lane = threadIdx.x & 63;
    int n0 = blockIdx.x * 16 + wv * 4;    // 16 nodes/block; N_NODES = 16*6250

    // 4 rows; lane holds feature pair (2*lane, 2*lane+1) of each
    float r0[4], r1[4];
#pragma unroll
    for (int r = 0; r < 4; r++) {
        float2 v = __half22float2(H2[(size_t)(n0 + r) * 64 + lane]);
        r0[r] = v.x;
        r1[r] = v.y;
    }

    float acc[4] = {0.f, 0.f, 0.f, 0.f};
#pragma unroll
    for (int f = 0; f < 64; f++) {
        float2 w = __half22float2(swp[f * 64 + lane]);   // W2[2f][lane], W2[2f+1][lane]
#pragma unroll
        for (int r = 0; r < 4; r++)
            acc[r] += bcf(r0[r], f) * w.x + bcf(r1[r], f) * w.y;
    }
#pragma unroll
    for (int r = 0; r < 4; r++)
        H3[(size_t)(n0 + r) * 64 + lane] = __float2half(acc[r]);
}

// ---------------- agg2: out = agg(h3) + b2, fp32 out ----------------

__global__ __launch_bounds__(256) void k_agg2(const __half* __restrict__ H3,
                                              const float* __restrict__ dinv,
                                              const int* __restrict__ rp,
                                              const int* __restrict__ col,
                                              const float* __restrict__ b2,
                                              float* __restrict__ out) {
    int node = (blockIdx.x * 256 + threadIdx.x) >> 6;
    int lane = threadIdx.x & 63;
    if (node >= N_NODES) return;

    float di = dinv[node];
    int e0 = rp[node], e1 = rp[node + 1];

    float a = __half2float(H3[(size_t)node * 64 + lane]) * di * di;

    for (int cb = e0; cb < e1; cb += 64) {
        int n = min(64, e1 - cb);
        int idx = cb + lane;
        int cv = col[idx < e1 ? idx : e0];
        float dv = dinv[cv];

        int j = 0;
        for (; j + 8 <= n; j += 8) {
            float hv[8];
            float w[8];
#pragma unroll
            for (int q = 0; q < 8; q++) {
                int s = bci(cv, j + q);
                w[q] = bcf(dv, j + q) * di;
                hv[q] = __half2float(H3[(size_t)s * 64 + lane]);
            }
#pragma unroll
            for (int q = 0; q < 8; q++) a += hv[q] * w[q];
        }
        for (; j < n; j++) {
            int s = bci(cv, j);
            float w = bcf(dv, j) * di;
            a += __half2float(H3[(size_t)s * 64 + lane]) * w;
        }
    }

    out[(size_t)node * 64 + lane] = a + b2[lane];
}

// ---------------- launch ----------------

extern "C" void kernel_launch(void* const* d_in, const int* in_sizes, int n_in,
                              void* d_out, int out_size, void* d_ws, size_t ws_size,
                              hipStream_t stream) {
    const float* x  = (const float*)d_in[0];
    const int*   ei = (const int*)d_in[1];
    const float* W1 = (const float*)d_in[2];
    const float* b1 = (const float*)d_in[3];
    const float* W2 = (const float*)d_in[4];
    const float* b2 = (const float*)d_in[5];
    float* out = (float*)d_out;

    const int* src = ei;
    const int* dst = ei + N_EDGES;

    char* ws = (char*)d_ws;
    size_t off = 0;
    auto alloc = [&](size_t bytes) -> void* {
        off = (off + 255) & ~(size_t)255;
        void* p = ws + off;
        off += bytes;
        return p;
    };
    int*     cnt  = (int*)alloc((size_t)N_NODES * 4);
    int*     fill = (int*)alloc((size_t)N_NODES * 4);
    int*     rp   = (int*)alloc((size_t)(N_NODES + 1) * 4);
    int*     bsum = (int*)alloc((size_t)NBLK * 4);
    int*     bo   = (int*)alloc((size_t)(NBLK + 1) * 4);
    float*   dinv = (float*)alloc((size_t)N_NODES * 4);
    int*     col  = (int*)alloc((size_t)N_EDGES * 4);
    __half2* h1   = (__half2*)alloc((size_t)N_NODES * 128 * 2);
    __half2* h2   = (__half2*)alloc((size_t)N_NODES * 128 * 2);
    __half*  h3   = (__half*)alloc((size_t)N_NODES * 64 * 2);

    hipMemsetAsync(cnt, 0, (size_t)N_NODES * 4, stream);
    hipMemsetAsync(fill, 0, (size_t)N_NODES * 4, stream);

    int ebl = (N_EDGES + 255) / 256;

    // CSR build (shared by both layers)
    k_count<<<ebl, 256, 0, stream>>>(dst, cnt);
    k_scan1<<<NBLK, 256, 0, stream>>>(cnt, rp, bsum, dinv);
    k_scan2<<<1, 512, 0, stream>>>(bsum, bo, NBLK);
    k_scan3<<<(N_NODES + 1 + 255) / 256, 256, 0, stream>>>(rp, bo, NBLK);
    k_fill<<<ebl, 256, 0, stream>>>(src, dst, rp, fill, col);

    // layer 1: h1 = x @ W1 ; h2 = relu(agg(h1) + b1)
    k_gemm1<<<N_NODES / 16, 256, 0, stream>>>(x, W1, h1);
    k_agg1<<<N_NODES / 4, 256, 0, stream>>>(h1, dinv, rp, col, b1, h2);

    // layer 2: h3 = h2 @ W2 ; out = agg(h3) + b2
    k_gemm2<<<N_NODES / 16, 256, 0, stream>>>(h2, W2, h3);
    k_agg2<<<(N_NODES * 64 + 255) / 256, 256, 0, stream>>>(h3, dinv, rp, col, b2, out);
}